// Round 8
// baseline (370.777 us; speedup 1.0000x reference)
//
#include <hip/hip_runtime.h>
#include <hip/hip_bf16.h>

// Problem constants
#define V_   16000
#define D_   1024
#define H_   1024
#define E_   8
#define C_   16
#define B_   64
#define S_   512
#define GH_  256
#define NPAIR 128   // B_ * K(=2)

typedef short  bf16x8 __attribute__((ext_vector_type(8)));
typedef ushort u16x8  __attribute__((ext_vector_type(8)));
typedef float  f32x4  __attribute__((ext_vector_type(4)));

static __device__ __forceinline__ ushort f2bf(float f) {
  union { float f; unsigned u; } un; un.f = f;
  unsigned u = un.u;
  return (ushort)((u + 0x7FFFu + ((u >> 16) & 1u)) >> 16);  // RNE
}

static __device__ __forceinline__ unsigned pk2(float lo, float hi) {
  __hip_bfloat162 h = __float22bfloat162_rn(make_float2(lo, hi));  // v_cvt_pk_bf16_f32
  unsigned r; __builtin_memcpy(&r, &h, sizeof(r)); return r;
}

static __device__ __forceinline__ uint4 cvt8(f32x4 a, f32x4 b) {
  uint4 w;
  w.x = pk2(a[0], a[1]); w.y = pk2(a[2], a[3]);
  w.z = pk2(b[0], b[1]); w.w = pk2(b[2], b[3]);
  return w;
}

// ---------------------------------------------------------------------------
// Kernel 0 (fused prep):
//  blocks [0,2048): repack exp_w1 (E,D,H) f32 -> w1t bf16 fragment tiles:
//   frag (e, hhalf, slab, ks, wr, fi) of 512 ushorts (64 lanes x 8) holds
//   A[h = hhalf*512 + wr*128 + fi*16 + (lane&15)]
//    [k = slab*64 + ks*32 + (lane>>4)*8 + j]
//   offset = (((((e*2+hhalf)*16 + slab)*2 + ks)*4 + wr)*8 + fi)*512 + lane*8
//  blocks [2048,2560): partial pooling partial[b][sb][d]
__global__ void prep_kernel(const float* __restrict__ w1, ushort* __restrict__ w1t,
                            const int* __restrict__ x, const float* __restrict__ emb,
                            float* __restrict__ partial) {
  __shared__ float tile[64][65];
  const int id = blockIdx.x;
  if (id < 2048) {
    const int e = id >> 8, rem = id & 255;
    const int dtile = rem & 15, htile = rem >> 4;   // dtile = k-slab, htile = 64-h tile
    const int d0 = dtile * 64, h0 = htile * 64;
    const float* src = w1 + (size_t)e * D_ * H_;
    for (int i = threadIdx.x; i < 64 * 64; i += 256) {
      int r = i >> 6, c = i & 63;                 // r: k-local, c: h-local
      tile[r][c] = src[(size_t)(d0 + r) * H_ + h0 + c];
    }
    __syncthreads();
    const int hhalf = htile >> 3;
    const int wr    = (htile >> 1) & 3;
    for (int i = threadIdx.x; i < 512; i += 256) {
      int c = i >> 6, lane = i & 63;
      int ks = c >> 2, fic = c & 3;
      int fi = ((htile & 1) << 2) | fic;
      int hl = (fic << 4) | (lane & 15);
      int kl = ks * 32 + ((lane >> 4) << 3);
      u16x8 v;
      #pragma unroll
      for (int j = 0; j < 8; ++j) v[j] = f2bf(tile[kl + j][hl]);
      size_t off = ((size_t)(((((e * 2 + hhalf) * 16 + dtile) * 2 + ks) * 4 + wr) * 8 + fi)) * 512
                   + lane * 8;
      *reinterpret_cast<u16x8*>(w1t + off) = v;
    }
  } else {
    const int pid = id - 2048;
    const int b = pid >> 3, sb = pid & 7, t = threadIdx.x;
    const int* xr = x + b * S_ + sb * 64;
    float4 acc = make_float4(0.f, 0.f, 0.f, 0.f);
    #pragma unroll 4
    for (int s = 0; s < 64; ++s) {
      const float4* row = reinterpret_cast<const float4*>(emb + (size_t)xr[s] * D_);
      float4 v = row[t];
      acc.x += v.x; acc.y += v.y; acc.z += v.z; acc.w += v.w;
    }
    reinterpret_cast<float4*>(partial + ((size_t)b * 8 + sb) * D_)[t] = acc;
  }
}

// ---------------------------------------------------------------------------
// Kernel 1: reduce partials + gating MLP + top-2 + renormalize (all f32)
__global__ void gate_kernel(const float* __restrict__ partial,
                            const float* __restrict__ gw1, const float* __restrict__ gb1,
                            const float* __restrict__ gw2, const float* __restrict__ gb2,
                            int* __restrict__ ridx, float* __restrict__ rwgt) {
  const int b = blockIdx.x, j = threadIdx.x;
  __shared__ float pl[D_];
  __shared__ float hid[GH_];
  __shared__ float logits[E_];
  for (int d = j; d < D_; d += 256) {
    float s = 0.f;
    #pragma unroll
    for (int sb = 0; sb < 8; ++sb) s += partial[((size_t)b * 8 + sb) * D_ + d];
    pl[d] = s * (1.f / (float)S_);
  }
  __syncthreads();
  float acc = gb1[j];
  for (int d = 0; d < D_; ++d) acc += pl[d] * gw1[d * GH_ + j];
  hid[j] = fmaxf(acc, 0.f);
  __syncthreads();
  if (j < E_) {
    float l = gb2[j];
    for (int i = 0; i < GH_; ++i) l += hid[i] * gw2[i * E_ + j];
    logits[j] = l;
  }
  __syncthreads();
  if (j == 0) {
    int i0 = 0; float v0 = logits[0];
    for (int i = 1; i < E_; ++i) if (logits[i] > v0) { v0 = logits[i]; i0 = i; }
    int i1 = -1; float v1 = -3.0e38f;
    for (int i = 0; i < E_; ++i) {
      if (i == i0) continue;
      if (logits[i] > v1) { v1 = logits[i]; i1 = i; }
    }
    float r1 = expf(v1 - v0);
    float norm = 1.f + r1;
    ridx[b * 2 + 0] = i0;         ridx[b * 2 + 1] = i1;
    rwgt[b * 2 + 0] = 1.f / norm; rwgt[b * 2 + 1] = r1 / norm;
  }
}

// ---------------------------------------------------------------------------
// Kernel 2: stable counting-rank sort of pairs by expert id. 1 block, 128 thr.
__global__ void sort_pairs_kernel(const int* __restrict__ ridx, int* __restrict__ order) {
  __shared__ int se[NPAIR];
  const int t = threadIdx.x;
  se[t] = ridx[t];
  __syncthreads();
  const int e = se[t];
  int rank = 0;
  for (int j = 0; j < NPAIR; ++j) {
    const int ej = se[j];
    rank += (ej < e || (ej == e && j < t)) ? 1 : 0;
  }
  order[rank] = t;
}

// ---------------------------------------------------------------------------
// Kernel 3: gathered GEMM + bias + ReLU + sum over s.
//   Block = (pair, hhalf, sblk): 512 h x 128 s, K = 1024 (16 slabs of 64).
//   A: 1 MiB fragment-ordered stream, global->VGPR; the two s-half waves of a
//      wave-row read IDENTICAL A addresses (L1 broadcast). Per-block K-phase
//      stagger (seq) decorrelates concurrent blocks' A requests on an XCD.
//   B: gathered tokens, 2-slot LDS slab ring (128 tok x 64 k bf16, swizzled),
//      gather issued 2 slabs ahead into a 2-deep reg ring.
// grid(1024), block 512 (8 waves = 4 h-rows x 2 s-halves; wave 128h x 64s)
__global__ __launch_bounds__(512, 2) void expert_kernel(
    const int* __restrict__ x, const float* __restrict__ exp_emb,
    const ushort* __restrict__ w1t, const float* __restrict__ exp_b1,
    const int* __restrict__ ridx, const int* __restrict__ order,
    float* __restrict__ p_part) {
  const int id     = blockIdx.x;           // 0..1023
  const int xcd    = id & 7;
  const int within = id >> 3;              // 0..127
  const int slot   = xcd * 128 + within;   // contiguous sorted chunk per XCD
  const int pr     = order[slot >> 3];
  const int sub    = slot & 7;
  const int sblk   = sub >> 1;             // 0..3  (128-token block)
  const int hhalf  = sub & 1;              // 0..1  (hh partners adjacent)
  const int b      = pr >> 1;
  const int tid    = threadIdx.x;

  __shared__ __align__(16) ushort lB[2][8192];   // 2 x 16 KiB slab ring

  const int e     = ridx[pr];
  const int phase = (pr * 3 + sblk * 5) & 15;    // hh-partners share phase

  // gather mapping: thread covers token row (tid>>2), 16 f32 at (tid&3)*16
  const int grow = tid >> 2, q = tid & 3;
  const int tok  = x[b * S_ + sblk * 128 + grow];
  const float* gptr = exp_emb + ((size_t)e * V_ + tok) * D_ + q * 16;
  const int swr = (grow & 7) << 3;
  const int bw0 = grow * 64 + ((q * 16) ^ swr);
  const int bw1 = grow * 64 + ((q * 16 + 8) ^ swr);

  const int wid = tid >> 6, lane = tid & 63;
  const int l15 = lane & 15, l16 = lane >> 4;
  const int ssel = wid >> 2, wr = wid & 3;

  // A fragment base: + slab*32768 + ks*16384 + fi*512
  const ushort* aBase = w1t + ((size_t)(e * 2 + hhalf) * 16) * 32768
                        + (size_t)wr * 4096 + (size_t)lane * 8;
  #define LOADA(slab_, ks_, fi_) (*reinterpret_cast<const bf16x8*>( \
      aBase + (size_t)(slab_) * 32768 + (ks_) * 16384 + (fi_) * 512))

  f32x4 acc[8][4];
  #pragma unroll
  for (int i = 0; i < 8; ++i)
    #pragma unroll
    for (int j = 0; j < 4; ++j) acc[i][j] = (f32x4){0.f, 0.f, 0.f, 0.f};

  f32x4 st[2][4];
  // ---- prologue: lB[0] <- seq(0); st[0] <- seq(1)
  {
    const int g0 = ((0 + phase) & 15) * 64;
    #pragma unroll
    for (int t = 0; t < 4; ++t)
      st[0][t] = __builtin_nontemporal_load(reinterpret_cast<const f32x4*>(gptr + g0 + t * 4));
    *reinterpret_cast<uint4*>(&lB[0][bw0]) = cvt8(st[0][0], st[0][1]);
    *reinterpret_cast<uint4*>(&lB[0][bw1]) = cvt8(st[0][2], st[0][3]);
    const int g1 = ((1 + phase) & 15) * 64;
    #pragma unroll
    for (int t = 0; t < 4; ++t)
      st[0][t] = __builtin_nontemporal_load(reinterpret_cast<const f32x4*>(gptr + g1 + t * 4));
  }
  __syncthreads();

  // ---- main loop: 16 slabs; invariant at iter s: lB[s&1]=seq(s), st[s&1]=seq(s+1)
  #pragma unroll
  for (int s = 0; s < 16; ++s) {
    const int cur = s & 1;
    const int kk  = (s + phase) & 15;
    // (a) issue gather for seq(s+2) into st[(s+1)&1]
    if (s + 2 < 16) {
      const int g = (((s + 2) + phase) & 15) * 64;
      #pragma unroll
      for (int t = 0; t < 4; ++t)
        st[(s + 1) & 1][t] =
            __builtin_nontemporal_load(reinterpret_cast<const f32x4*>(gptr + g + t * 4));
    }
    // (b) compute A(kk) x lB[cur]
    #pragma unroll
    for (int ks = 0; ks < 2; ++ks) {
      bf16x8 bfr[4];
      #pragma unroll
      for (int sj = 0; sj < 4; ++sj) {
        const int srow = ssel * 64 + sj * 16 + l15;
        bfr[sj] = *reinterpret_cast<const bf16x8*>(
            &lB[cur][srow * 64 + ((ks * 32 + l16 * 8) ^ ((srow & 7) << 3))]);
      }
      #pragma unroll
      for (int half = 0; half < 2; ++half) {
        bf16x8 af[4];
        #pragma unroll
        for (int f = 0; f < 4; ++f) af[f] = LOADA(kk, ks, half * 4 + f);
        #pragma unroll
        for (int f = 0; f < 4; ++f)
          #pragma unroll
          for (int sj = 0; sj < 4; ++sj)
            acc[half * 4 + f][sj] = __builtin_amdgcn_mfma_f32_16x16x32_bf16(
                af[f], bfr[sj], acc[half * 4 + f][sj], 0, 0, 0);
      }
    }
    // (c) write lB[cur^1] <- st[s&1] (seq(s+1))
    if (s + 1 < 16) {
      *reinterpret_cast<uint4*>(&lB[cur ^ 1][bw0]) = cvt8(st[cur][0], st[cur][1]);
      *reinterpret_cast<uint4*>(&lB[cur ^ 1][bw1]) = cvt8(st[cur][2], st[cur][3]);
    }
    __syncthreads();
  }
  #undef LOADA

  // ---- epilogue: + bias, ReLU, sum over this wave's 64 s columns
  float* outRow = p_part + ((size_t)((sblk * 2 + ssel) * NPAIR + pr)) * H_
                  + hhalf * 512 + wr * 128;
  const float* biasE = exp_b1 + e * H_ + hhalf * 512 + wr * 128;
  #pragma unroll
  for (int fi = 0; fi < 8; ++fi) {
    #pragma unroll
    for (int r = 0; r < 4; ++r) {
      const int hl = fi * 16 + l16 * 4 + r;
      const float bias = biasE[hl];
      float v = 0.f;
      #pragma unroll
      for (int sj = 0; sj < 4; ++sj) v += fmaxf(acc[fi][sj][r] + bias, 0.f);
      #pragma unroll
      for (int m = 1; m < 16; m <<= 1) v += __shfl_xor(v, m);  // reduce 16 s-cols
      if (l15 == 0) outRow[hl] = v;
    }
  }
}

// ---------------------------------------------------------------------------
// Kernel 4: out[b][c] = sum_k rw * ( (sum_sb p_part)/S @ W2[e] + b2[e] )
__global__ void finalize_kernel(const float* __restrict__ p_part,
                                const int* __restrict__ ridx, const float* __restrict__ rwgt,
                                const float* __restrict__ w2, const float* __restrict__ b2,
                                float* __restrict__ out) {
  const int b = blockIdx.x, t = threadIdx.x;
  const int c = t & 15, g = t >> 4;
  __shared__ float red[16][17];
  float res = 0.f;
  for (int kk = 0; kk < 2; ++kk) {
    const int pr = b * 2 + kk;
    const int e = ridx[pr];
    const float w = rwgt[pr];
    float dot = 0.f;
    for (int h = g; h < H_; h += 16) {
      float pm = 0.f;
      #pragma unroll
      for (int sb = 0; sb < 8; ++sb) pm += p_part[(size_t)(sb * NPAIR + pr) * H_ + h];
      dot += pm * w2[((size_t)e * H_ + h) * C_ + c];
    }
    red[g][c] = dot;
    __syncthreads();
    if (g == 0) {
      float s = 0.f;
      #pragma unroll
      for (int i = 0; i < 16; ++i) s += red[i][c];
      res += w * (s * (1.f / (float)S_) + b2[e * C_ + c]);
    }
    __syncthreads();
  }
  if (g == 0) out[b * C_ + c] = res;
}

// ---------------------------------------------------------------------------
extern "C" void kernel_launch(void* const* d_in, const int* in_sizes, int n_in,
                              void* d_out, int out_size, void* d_ws, size_t ws_size,
                              hipStream_t stream) {
  const int*   x    = (const int*)  d_in[0];
  const float* emb  = (const float*)d_in[1];
  const float* gw1  = (const float*)d_in[2];
  const float* gb1  = (const float*)d_in[3];
  const float* gw2  = (const float*)d_in[4];
  const float* gb2  = (const float*)d_in[5];
  const float* eemb = (const float*)d_in[6];
  const float* ew1  = (const float*)d_in[7];
  const float* eb1  = (const float*)d_in[8];
  const float* ew2  = (const float*)d_in[9];
  const float* eb2  = (const float*)d_in[10];
  float* out = (float*)d_out;

  char* ws = (char*)d_ws;
  const size_t OFF_W1T   = 0;                            // 16 MiB
  const size_t OFF_PART  = (size_t)16 << 20;             // 2 MiB
  const size_t OFF_RIDX  = OFF_PART + ((size_t)2 << 20);
  const size_t OFF_RWGT  = OFF_RIDX + 1024;
  const size_t OFF_ORDER = OFF_RWGT + 1024;
  const size_t OFF_PPART = OFF_ORDER + 1024;             // 4 MiB

  ushort* w1t    = (ushort*)(ws + OFF_W1T);
  float*  part   = (float*) (ws + OFF_PART);
  int*    ridx   = (int*)   (ws + OFF_RIDX);
  float*  rwgt   = (float*) (ws + OFF_RWGT);
  int*    order  = (int*)   (ws + OFF_ORDER);
  float*  ppart  = (float*) (ws + OFF_PPART);

  prep_kernel<<<dim3(2560), 256, 0, stream>>>(ew1, w1t, x, emb, part);
  gate_kernel<<<dim3(B_), 256, 0, stream>>>(part, gw1, gb1, gw2, gb2, ridx, rwgt);
  sort_pairs_kernel<<<dim3(1), 128, 0, stream>>>(ridx, order);
  expert_kernel<<<dim3(1024), 512, 0, stream>>>(x, eemb, w1t, eb1, ridx, order, ppart);
  finalize_kernel<<<dim3(B_), 256, 0, stream>>>(ppart, ridx, rwgt, ew2, eb2, out);
}

// Round 9
// 361.664 us; speedup vs baseline: 1.0252x; 1.0252x over previous
//
#include <hip/hip_runtime.h>
#include <hip/hip_bf16.h>

// Problem constants
#define V_   16000
#define D_   1024
#define H_   1024
#define E_   8
#define C_   16
#define B_   64
#define S_   512
#define GH_  256
#define NPAIR 128   // B_ * K(=2)

typedef short  bf16x8 __attribute__((ext_vector_type(8)));
typedef ushort u16x8  __attribute__((ext_vector_type(8)));
typedef float  f32x4  __attribute__((ext_vector_type(4)));
typedef float  f32x16 __attribute__((ext_vector_type(16)));

static __device__ __forceinline__ ushort f2bf(float f) {
  union { float f; unsigned u; } un; un.f = f;
  unsigned u = un.u;
  return (ushort)((u + 0x7FFFu + ((u >> 16) & 1u)) >> 16);  // RNE
}

static __device__ __forceinline__ unsigned pk2(float lo, float hi) {
  __hip_bfloat162 h = __float22bfloat162_rn(make_float2(lo, hi));  // v_cvt_pk_bf16_f32
  unsigned r; __builtin_memcpy(&r, &h, sizeof(r)); return r;
}

static __device__ __forceinline__ uint4 cvt8(f32x4 a, f32x4 b) {
  uint4 w;
  w.x = pk2(a[0], a[1]); w.y = pk2(a[2], a[3]);
  w.z = pk2(b[0], b[1]); w.w = pk2(b[2], b[3]);
  return w;
}

// ---------------------------------------------------------------------------
// Kernel 0 (fused prep):
//  blocks [0,2048): repack exp_w1 (E,D,H) f32 -> w1t bf16, 32x32x16 A-frags:
//   chunk t = slab*4 + ks (k in [slab*64 + ks*16, +16)); frag hf (32 h rows).
//   ushort addr = (e*64 + t)*16384 + hf*512 + lane*8, element j:
//     A[h = hf*32 + (lane&31)][k = slab*64 + ks*16 + (lane>>5)*8 + j]
//  blocks [2048,2560): partial pooling partial[b][sb][d]
__global__ void prep_kernel(const float* __restrict__ w1, ushort* __restrict__ w1t,
                            const int* __restrict__ x, const float* __restrict__ emb,
                            float* __restrict__ partial) {
  __shared__ float tile[64][65];
  const int id = blockIdx.x;
  if (id < 2048) {
    const int e = id >> 8, rem = id & 255;
    const int dtile = rem & 15, htile = rem >> 4;   // dtile = k-slab, htile = 64-h tile
    const int d0 = dtile * 64, h0 = htile * 64;
    const float* src = w1 + (size_t)e * D_ * H_;
    for (int i = threadIdx.x; i < 64 * 64; i += 256) {
      int r = i >> 6, c = i & 63;                 // r: k-local, c: h-local
      tile[r][c] = src[(size_t)(d0 + r) * H_ + h0 + c];
    }
    __syncthreads();
    for (int i = threadIdx.x; i < 512; i += 256) {
      int c = i >> 6, lane = i & 63;
      int ks = c >> 1, hfl = c & 1;
      int hl = hfl * 32 + (lane & 31);
      int kl = ks * 16 + ((lane >> 5) << 3);
      u16x8 v;
      #pragma unroll
      for (int j = 0; j < 8; ++j) v[j] = f2bf(tile[kl + j][hl]);
      const int t  = dtile * 4 + ks;
      const int hf = htile * 2 + hfl;
      size_t off = ((size_t)(e * 64 + t)) * 16384 + hf * 512 + lane * 8;
      *reinterpret_cast<u16x8*>(w1t + off) = v;
    }
  } else {
    const int pid = id - 2048;
    const int b = pid >> 3, sb = pid & 7, t = threadIdx.x;
    const int* xr = x + b * S_ + sb * 64;
    float4 acc = make_float4(0.f, 0.f, 0.f, 0.f);
    #pragma unroll 4
    for (int s = 0; s < 64; ++s) {
      const float4* row = reinterpret_cast<const float4*>(emb + (size_t)xr[s] * D_);
      float4 v = row[t];
      acc.x += v.x; acc.y += v.y; acc.z += v.z; acc.w += v.w;
    }
    reinterpret_cast<float4*>(partial + ((size_t)b * 8 + sb) * D_)[t] = acc;
  }
}

// ---------------------------------------------------------------------------
// Kernel 1: reduce partials + gating MLP + top-2 + renormalize (all f32)
__global__ void gate_kernel(const float* __restrict__ partial,
                            const float* __restrict__ gw1, const float* __restrict__ gb1,
                            const float* __restrict__ gw2, const float* __restrict__ gb2,
                            int* __restrict__ ridx, float* __restrict__ rwgt) {
  const int b = blockIdx.x, j = threadIdx.x;
  __shared__ float pl[D_];
  __shared__ float hid[GH_];
  __shared__ float logits[E_];
  for (int d = j; d < D_; d += 256) {
    float s = 0.f;
    #pragma unroll
    for (int sb = 0; sb < 8; ++sb) s += partial[((size_t)b * 8 + sb) * D_ + d];
    pl[d] = s * (1.f / (float)S_);
  }
  __syncthreads();
  float acc = gb1[j];
  for (int d = 0; d < D_; ++d) acc += pl[d] * gw1[d * GH_ + j];
  hid[j] = fmaxf(acc, 0.f);
  __syncthreads();
  if (j < E_) {
    float l = gb2[j];
    for (int i = 0; i < GH_; ++i) l += hid[i] * gw2[i * E_ + j];
    logits[j] = l;
  }
  __syncthreads();
  if (j == 0) {
    int i0 = 0; float v0 = logits[0];
    for (int i = 1; i < E_; ++i) if (logits[i] > v0) { v0 = logits[i]; i0 = i; }
    int i1 = -1; float v1 = -3.0e38f;
    for (int i = 0; i < E_; ++i) {
      if (i == i0) continue;
      if (logits[i] > v1) { v1 = logits[i]; i1 = i; }
    }
    float r1 = expf(v1 - v0);
    float norm = 1.f + r1;
    ridx[b * 2 + 0] = i0;         ridx[b * 2 + 1] = i1;
    rwgt[b * 2 + 0] = 1.f / norm; rwgt[b * 2 + 1] = r1 / norm;
  }
}

// ---------------------------------------------------------------------------
// Kernel 2: stable counting-rank sort of pairs by expert id. 1 block, 128 thr.
__global__ void sort_pairs_kernel(const int* __restrict__ ridx, int* __restrict__ order) {
  __shared__ int se[NPAIR];
  const int t = threadIdx.x;
  se[t] = ridx[t];
  __syncthreads();
  const int e = se[t];
  int rank = 0;
  for (int j = 0; j < NPAIR; ++j) {
    const int ej = se[j];
    rank += (ej < e || (ej == e && j < t)) ? 1 : 0;
  }
  order[rank] = t;
}

// ---------------------------------------------------------------------------
// Kernel 3: token-stationary gathered GEMM + bias + ReLU + sum over s.
//   Round-4 structure, 32x32x16 MFMA. Block = 64 tokens x ALL H, K=1024.
//   B (tokens): fragment-ordered LDS slab ring (2 x 8 KiB); writer scatters
//     gathered f32->bf16 straight into MFMA B-frag order; reads are linear
//     lane*16 ds_read_b128 (conflict-free). Gather 2 slabs ahead (NT, regs).
//   A (w1t): fragment-direct global->VGPR, 1-chunk-deep prefetch; per wave
//     32 MFMA + 16 A-loads + 2 ds_reads per K=64 slab (half round-4's count).
// grid(1024), block 512 (8 waves; wave = 128h x 64s); sort + XCD-chunked.
__global__ __launch_bounds__(512, 2) void expert_kernel(
    const int* __restrict__ x, const float* __restrict__ exp_emb,
    const ushort* __restrict__ w1t, const float* __restrict__ exp_b1,
    const int* __restrict__ ridx, const int* __restrict__ order,
    float* __restrict__ p_part) {
  const int id     = blockIdx.x;           // 0..1023
  const int xcd    = id & 7;
  const int within = id >> 3;              // 0..127
  const int slot   = xcd * 128 + within;   // contiguous sorted chunk per XCD
  const int pr     = order[slot >> 3];
  const int sblk   = slot & 7;
  const int b      = pr >> 1;
  const int tid    = threadIdx.x;

  __shared__ __align__(16) ushort lB[2][4096];   // 2 x 8 KiB B slab ring

  const int e = ridx[pr];

  // gather mapping: thread (grow, q, jh) loads 8 f32 of token row grow at
  // k = slab*64 + q*16 + jh*8; writes 16B into B-frag (ks=q, sf=grow>>5),
  // lane = (grow&31) + 32*jh.
  const int grow = tid >> 3, sub = tid & 7;
  const int q = sub >> 1, jh = sub & 1;
  const int tok  = x[b * S_ + sblk * 64 + grow];
  const float* gptr = exp_emb + ((size_t)e * V_ + tok) * D_ + q * 16 + jh * 8;
  const int bwidx = ((q * 2 + (grow >> 5)) * 64 + (grow & 31) + 32 * jh) * 8;

  const int wid = tid >> 6, lane = tid & 63;
  const int l31 = lane & 31, lh = lane >> 5;

  // A fragment stream: chunk t = slab*4+ks; frag f: wave wid owns hf=wid*4+f
  const ushort* aBase = w1t + (size_t)e * (64 * 16384) + (wid * 4) * 512 + lane * 8;
  #define LOADA_T(t_, f_) (*reinterpret_cast<const bf16x8*>( \
      aBase + (size_t)(t_) * 16384 + (f_) * 512))

  f32x16 acc[4][2];
  #pragma unroll
  for (int f = 0; f < 4; ++f)
    #pragma unroll
    for (int sf = 0; sf < 2; ++sf)
      #pragma unroll
      for (int r = 0; r < 16; ++r) acc[f][sf][r] = 0.f;

  f32x4 st[2][2];
  bf16x8 af[4], afn[4];

  // ---- prologue: slab 0 -> lB[0]; slab 1 -> st[1]; A chunk 0 -> af
  st[0][0] = __builtin_nontemporal_load(reinterpret_cast<const f32x4*>(gptr));
  st[0][1] = __builtin_nontemporal_load(reinterpret_cast<const f32x4*>(gptr + 4));
  *reinterpret_cast<uint4*>(&lB[0][bwidx]) = cvt8(st[0][0], st[0][1]);
  st[1][0] = __builtin_nontemporal_load(reinterpret_cast<const f32x4*>(gptr + 64));
  st[1][1] = __builtin_nontemporal_load(reinterpret_cast<const f32x4*>(gptr + 68));
  #pragma unroll
  for (int f = 0; f < 4; ++f) af[f] = LOADA_T(0, f);
  __syncthreads();

  // ---- main loop: 16 slabs; at iter s: lB[s&1] = slab s, st[(s+1)&1] = slab s+1
  #pragma unroll
  for (int s = 0; s < 16; ++s) {
    const int cur = s & 1;
    // (a) issue gather for slab s+2 into st[cur] (parity (s+2)&1 == cur)
    if (s + 2 < 16) {
      st[cur][0] = __builtin_nontemporal_load(
          reinterpret_cast<const f32x4*>(gptr + (s + 2) * 64));
      st[cur][1] = __builtin_nontemporal_load(
          reinterpret_cast<const f32x4*>(gptr + (s + 2) * 64 + 4));
    }
    // (b) 4 chunks of K=16, 8 MFMA each; 1-deep A prefetch
    #pragma unroll
    for (int ks = 0; ks < 4; ++ks) {
      const int t = s * 4 + ks;
      if (t + 1 < 64) {
        #pragma unroll
        for (int f = 0; f < 4; ++f) afn[f] = LOADA_T(t + 1, f);
      }
      bf16x8 bf[2];
      #pragma unroll
      for (int sf = 0; sf < 2; ++sf)
        bf[sf] = *reinterpret_cast<const bf16x8*>(&lB[cur][((ks * 2 + sf) * 64 + lane) * 8]);
      #pragma unroll
      for (int f = 0; f < 4; ++f)
        #pragma unroll
        for (int sf = 0; sf < 2; ++sf)
          acc[f][sf] = __builtin_amdgcn_mfma_f32_32x32x16_bf16(af[f], bf[sf], acc[f][sf], 0, 0, 0);
      #pragma unroll
      for (int f = 0; f < 4; ++f) af[f] = afn[f];
    }
    // (c) write slab s+1 into lB[cur^1] (its readers finished at barrier s-1)
    if (s + 1 < 16) {
      const int p = (s + 1) & 1;
      *reinterpret_cast<uint4*>(&lB[p][bwidx]) = cvt8(st[p][0], st[p][1]);
    }
    __syncthreads();
  }
  #undef LOADA_T

  // ---- epilogue: + bias, ReLU, sum over 64 s cols (32-lane shuffle), store
  // C/D 32x32 mapping: col = lane&31 (s), row = (reg&3) + 8*(reg>>2) + 4*(lane>>5)
  float* outRow = p_part + (size_t)(sblk * NPAIR + pr) * H_ + wid * 128;
  const float* biasE = exp_b1 + e * H_ + wid * 128;
  #pragma unroll
  for (int f = 0; f < 4; ++f) {
    #pragma unroll
    for (int reg = 0; reg < 16; ++reg) {
      const int h = f * 32 + (reg & 3) + 8 * (reg >> 2) + 4 * lh;
      const float bias = biasE[h];
      float v = fmaxf(acc[f][0][reg] + bias, 0.f) + fmaxf(acc[f][1][reg] + bias, 0.f);
      v += __shfl_xor(v, 1);  v += __shfl_xor(v, 2);  v += __shfl_xor(v, 4);
      v += __shfl_xor(v, 8);  v += __shfl_xor(v, 16);
      if (l31 == 0) outRow[h] = v;
    }
  }
}

// ---------------------------------------------------------------------------
// Kernel 4: out[b][c] = sum_k rw * ( (sum_sb p_part)/S @ W2[e] + b2[e] )
__global__ void finalize_kernel(const float* __restrict__ p_part,
                                const int* __restrict__ ridx, const float* __restrict__ rwgt,
                                const float* __restrict__ w2, const float* __restrict__ b2,
                                float* __restrict__ out) {
  const int b = blockIdx.x, t = threadIdx.x;
  const int c = t & 15, g = t >> 4;
  __shared__ float red[16][17];
  float res = 0.f;
  for (int kk = 0; kk < 2; ++kk) {
    const int pr = b * 2 + kk;
    const int e = ridx[pr];
    const float w = rwgt[pr];
    float dot = 0.f;
    for (int h = g; h < H_; h += 16) {
      float pm = 0.f;
      #pragma unroll
      for (int sb = 0; sb < 8; ++sb) pm += p_part[(size_t)(sb * NPAIR + pr) * H_ + h];
      dot += pm * w2[((size_t)e * H_ + h) * C_ + c];
    }
    red[g][c] = dot;
    __syncthreads();
    if (g == 0) {
      float s = 0.f;
      #pragma unroll
      for (int i = 0; i < 16; ++i) s += red[i][c];
      res += w * (s * (1.f / (float)S_) + b2[e * C_ + c]);
    }
    __syncthreads();
  }
  if (g == 0) out[b * C_ + c] = res;
}

// ---------------------------------------------------------------------------
extern "C" void kernel_launch(void* const* d_in, const int* in_sizes, int n_in,
                              void* d_out, int out_size, void* d_ws, size_t ws_size,
                              hipStream_t stream) {
  const int*   x    = (const int*)  d_in[0];
  const float* emb  = (const float*)d_in[1];
  const float* gw1  = (const float*)d_in[2];
  const float* gb1  = (const float*)d_in[3];
  const float* gw2  = (const float*)d_in[4];
  const float* gb2  = (const float*)d_in[5];
  const float* eemb = (const float*)d_in[6];
  const float* ew1  = (const float*)d_in[7];
  const float* eb1  = (const float*)d_in[8];
  const float* ew2  = (const float*)d_in[9];
  const float* eb2  = (const float*)d_in[10];
  float* out = (float*)d_out;

  char* ws = (char*)d_ws;
  const size_t OFF_W1T   = 0;                            // 16 MiB
  const size_t OFF_PART  = (size_t)16 << 20;             // 2 MiB
  const size_t OFF_RIDX  = OFF_PART + ((size_t)2 << 20);
  const size_t OFF_RWGT  = OFF_RIDX + 1024;
  const size_t OFF_ORDER = OFF_RWGT + 1024;
  const size_t OFF_PPART = OFF_ORDER + 1024;             // 4 MiB

  ushort* w1t    = (ushort*)(ws + OFF_W1T);
  float*  part   = (float*) (ws + OFF_PART);
  int*    ridx   = (int*)   (ws + OFF_RIDX);
  float*  rwgt   = (float*) (ws + OFF_RWGT);
  int*    order  = (int*)   (ws + OFF_ORDER);
  float*  ppart  = (float*) (ws + OFF_PPART);

  prep_kernel<<<dim3(2560), 256, 0, stream>>>(ew1, w1t, x, emb, part);
  gate_kernel<<<dim3(B_), 256, 0, stream>>>(part, gw1, gb1, gw2, gb2, ridx, rwgt);
  sort_pairs_kernel<<<dim3(1), 128, 0, stream>>>(ridx, order);
  expert_kernel<<<dim3(1024), 512, 0, stream>>>(x, eemb, w1t, eb1, ridx, order, ppart);
  finalize_kernel<<<dim3(B_), 256, 0, stream>>>(ppart, ridx, rwgt, ew2, eb2, out);
}